// Round 2
// baseline (382.735 us; speedup 1.0000x reference)
//
#include <hip/hip_runtime.h>

// Dota2Eq3Embed: 2048 samples x 2 sides. Per (n,side):
//   v[i][d] = relu(embed[x[n,side,i]][d]), i<5, d<64
//   The 8 equivariant basis contractions of the rank-1 cube v_i v_j v_k
//   reduce to per-channel tables over {v_iv_jv_k, S*v_iv_j, S^2*v_i, S^3};
//   mean-pool commutes with wout. 96 FMAs per d per channel.
// Output: (2048, 2) f32.

#define DEV __device__ __forceinline__

DEV constexpr int pid2(int a, int b) {
  int x = a < b ? a : b;
  int y = a < b ? b : a;
  return x * (9 - x) / 2 + y;            // 15 symmetric pairs, lexicographic
}
DEV constexpr int tid3(int i, int j, int k) {
  int a = i, b = j, c = k, t;
  if (a > b) { t = a; a = b; b = t; }
  if (b > c) { t = b; b = c; c = t; }
  if (a > b) { t = a; a = b; b = t; }
  return a * (a * a - 18 * a + 107) / 6 + (b - a) * (11 - a - b) / 2 + (c - b);
}

// Feature row layout (60 floats + 4 pad, 15 float4 groups, row stride 64):
//   [0..34]  triples v_a v_b v_c          (pad 35)
//   [36..50] S * pairs                    (pad 51)
//   [52..56] S^2 * v_i
//   [57]     S^3                          (pad 58,59; groups 15 unused)
// Physical group = logical g ^ (d & 15)  -> conflict-free b128 writes
// (reads are wave-uniform broadcast, layout-agnostic).

__global__ __launch_bounds__(256, 4)
void dota2_eq3_kernel(const int* __restrict__ x,
                      const float* __restrict__ embed,
                      const float* __restrict__ coefs1, const float* __restrict__ bias1,
                      const float* __restrict__ wout1,  const float* __restrict__ bout1,
                      const float* __restrict__ coefs2, const float* __restrict__ bias2,
                      const float* __restrict__ wout2,  const float* __restrict__ bout2,
                      const float* __restrict__ fcw,    const float* __restrict__ fcb,
                      float* __restrict__ out)
{
  __shared__ __align__(16) float Feat[2][64][64];
  __shared__ __align__(16) float hbarL[2][128];
  __shared__ __align__(16) float zL[256];

  const int n    = blockIdx.x;
  const int tid  = threadIdx.x;
  const int side = tid >> 7;          // waves 0,1 -> side 0; waves 2,3 -> side 1
  const int t2   = tid & 127;

  // ---------- Phase A: build per-d feature rows (threads t2<64, d=t2) ----------
  if (t2 < 64) {
    const int d = t2;
    const int* xn = x + n * 10 + side * 5;
    float v[5];
    #pragma unroll
    for (int i = 0; i < 5; ++i) v[i] = fmaxf(embed[xn[i] * 64 + d], 0.f);
    const float S  = v[0] + v[1] + v[2] + v[3] + v[4];
    const float S2 = S * S;
    const float S3 = S2 * S;
    float p2[15];
    {
      int c2 = 0;
      #pragma unroll
      for (int a = 0; a < 5; ++a)
        #pragma unroll
        for (int b = a; b < 5; ++b) { p2[c2] = v[a] * v[b]; ++c2; }
    }
    alignas(16) float fr[60];
    {
      int c3 = 0;
      #pragma unroll
      for (int a = 0; a < 5; ++a)
        #pragma unroll
        for (int b = a; b < 5; ++b)
          #pragma unroll
          for (int c = b; c < 5; ++c) { fr[c3] = p2[pid2(a, b)] * v[c]; ++c3; }
    }
    fr[35] = 0.f;
    #pragma unroll
    for (int t = 0; t < 15; ++t) fr[36 + t] = S * p2[t];
    fr[51] = 0.f;
    #pragma unroll
    for (int i = 0; i < 5; ++i)  fr[52 + i] = S2 * v[i];
    fr[57] = S3;
    fr[58] = 0.f; fr[59] = 0.f;

    const int sw = d & 15;
    const float4* frv = reinterpret_cast<const float4*>(fr);
    float* row = &Feat[side][d][0];
    #pragma unroll
    for (int g = 0; g < 15; ++g)
      *reinterpret_cast<float4*>(row + ((g ^ sw) << 2)) = frv[g];
  }
  __syncthreads();

  // ---------- Phase B: contraction over d (thread = channel s) ----------
  const int s = t2;
  const float* Cb = side ? coefs2 : coefs1;
  const float* bi = side ? bias2  : bias1;

  float g0[35], b1a[15], b2a[15], b3a[15], m4[5], m5[5], m6[5];
  float a7 = 0.f;
  #pragma unroll
  for (int t = 0; t < 35; ++t) g0[t] = 0.f;
  #pragma unroll
  for (int t = 0; t < 15; ++t) { b1a[t] = 0.f; b2a[t] = 0.f; b3a[t] = 0.f; }
  #pragma unroll
  for (int t = 0; t < 5; ++t)  { m4[t] = 0.f; m5[t] = 0.f; m6[t] = 0.f; }

  const float* Cs = Cb + s * 8;       // coefs[d][s][b], b contiguous, 32B-aligned
  float4 cA = *reinterpret_cast<const float4*>(Cs);
  float4 cB = *reinterpret_cast<const float4*>(Cs + 4);

  #pragma unroll 1
  for (int d = 0; d < 64; ++d) {
    // prefetch next d's coefs (wraps to 0 at d=63; harmless in-bounds load)
    const float* cpn = Cs + (size_t)((d + 1) & 63) * 1024;
    const float4 nA = *reinterpret_cast<const float4*>(cpn);
    const float4 nB = *reinterpret_cast<const float4*>(cpn + 4);

    const float* Fd = &Feat[side][d][0];
    const int sw = d & 15;
    alignas(16) float F[60];
    float4* Fv = reinterpret_cast<float4*>(F);
    #pragma unroll
    for (int g = 0; g < 15; ++g)
      Fv[g] = *reinterpret_cast<const float4*>(Fd + ((g ^ sw) << 2));

    #pragma unroll
    for (int t = 0; t < 35; ++t) g0[t] = fmaf(cA.x, F[t], g0[t]);
    #pragma unroll
    for (int t = 0; t < 15; ++t) {
      const float w = F[36 + t];
      b1a[t] = fmaf(cA.y, w, b1a[t]);
      b2a[t] = fmaf(cA.z, w, b2a[t]);
      b3a[t] = fmaf(cA.w, w, b3a[t]);
    }
    #pragma unroll
    for (int t = 0; t < 5; ++t) {
      const float u = F[52 + t];
      m4[t] = fmaf(cB.x, u, m4[t]);
      m5[t] = fmaf(cB.y, u, m5[t]);
      m6[t] = fmaf(cB.z, u, m6[t]);
    }
    a7 = fmaf(cB.w, F[57], a7);

    cA = nA; cB = nB;
  }

  // ---------- Assembly: mean of relu over 125 positions (constexpr indices) ----------
  float hsum = 0.f;
  const float base = a7 + bi[s];
  #pragma unroll
  for (int i = 0; i < 5; ++i) {
    const float pi = base + m6[i];
    #pragma unroll
    for (int j = 0; j < 5; ++j) {
      const float pij = pi + m5[j] + b3a[pid2(i, j)];
      #pragma unroll
      for (int k = 0; k < 5; ++k) {
        const float val = pij + m4[k] + b2a[pid2(i, k)] + b1a[pid2(j, k)] + g0[tid3(i, j, k)];
        hsum += fmaxf(val, 0.f);
      }
    }
  }
  hbarL[side][s] = hsum * (1.f / 125.f);
  __syncthreads();

  // ---------- Phase C: te[o] = relu(hbar @ wout + bout), per side ----------
  {
    const int o = t2;
    const float* W  = side ? wout2 : wout1;
    const float* bo = side ? bout2 : bout1;
    const float* hb = &hbarL[side][0];
    float a0 = 0.f, a1 = 0.f, a2 = 0.f, a3 = 0.f;
    #pragma unroll 4
    for (int ss = 0; ss < 128; ss += 4) {
      a0 = fmaf(hb[ss + 0], W[(ss + 0) * 128 + o], a0);
      a1 = fmaf(hb[ss + 1], W[(ss + 1) * 128 + o], a1);
      a2 = fmaf(hb[ss + 2], W[(ss + 2) * 128 + o], a2);
      a3 = fmaf(hb[ss + 3], W[(ss + 3) * 128 + o], a3);
    }
    zL[side * 128 + o] = fmaxf(bo[o] + ((a0 + a1) + (a2 + a3)), 0.f);
  }
  __syncthreads();

  // ---------- Phase D: final FC (256 -> 2), wave-parallel ----------
  if (tid < 64) {
    const float4 zq = *reinterpret_cast<const float4*>(&zL[tid * 4]);
    const int q = tid * 4;
    float p0 = 0.f, p1 = 0.f;
    p0 = fmaf(zq.x, fcw[(q + 0) * 2 + 0], p0);
    p1 = fmaf(zq.x, fcw[(q + 0) * 2 + 1], p1);
    p0 = fmaf(zq.y, fcw[(q + 1) * 2 + 0], p0);
    p1 = fmaf(zq.y, fcw[(q + 1) * 2 + 1], p1);
    p0 = fmaf(zq.z, fcw[(q + 2) * 2 + 0], p0);
    p1 = fmaf(zq.z, fcw[(q + 2) * 2 + 1], p1);
    p0 = fmaf(zq.w, fcw[(q + 3) * 2 + 0], p0);
    p1 = fmaf(zq.w, fcw[(q + 3) * 2 + 1], p1);
    #pragma unroll
    for (int off = 32; off; off >>= 1) {
      p0 += __shfl_down(p0, off);
      p1 += __shfl_down(p1, off);
    }
    if (tid == 0) {
      out[n * 2 + 0] = p0 + fcb[0];
      out[n * 2 + 1] = p1 + fcb[1];
    }
  }
}

extern "C" void kernel_launch(void* const* d_in, const int* in_sizes, int n_in,
                              void* d_out, int out_size, void* d_ws, size_t ws_size,
                              hipStream_t stream) {
  const int*   x      = (const int*)  d_in[0];
  const float* embed  = (const float*)d_in[1];
  const float* coefs1 = (const float*)d_in[2];
  const float* bias1  = (const float*)d_in[3];
  const float* wout1  = (const float*)d_in[4];
  const float* bout1  = (const float*)d_in[5];
  const float* coefs2 = (const float*)d_in[6];
  const float* bias2  = (const float*)d_in[7];
  const float* wout2  = (const float*)d_in[8];
  const float* bout2  = (const float*)d_in[9];
  const float* fcw    = (const float*)d_in[10];
  const float* fcb    = (const float*)d_in[11];
  float* out = (float*)d_out;

  const int batch = in_sizes[0] / 10;   // x: (B, 2, 5)
  dota2_eq3_kernel<<<batch, 256, 0, stream>>>(
      x, embed, coefs1, bias1, wout1, bout1,
      coefs2, bias2, wout2, bout2, fcw, fcb, out);
}

// Round 3
// 135.840 us; speedup vs baseline: 2.8175x; 2.8175x over previous
//
#include <hip/hip_runtime.h>

// Dota2Eq3Embed: 2048 samples x 2 sides. Per (n,side):
//   v[i][d] = relu(embed[x[n,side,i]][d]), i<5, d<64
//   The 8 equivariant basis contractions of the rank-1 cube v_i v_j v_k
//   reduce to per-channel tables over {v_iv_jv_k, S*v_iv_j, S^2*v_i, S^3};
//   mean-pool commutes with wout. 96 FMAs per d per channel.
// Output: (2048, 2) f32.
//
// Register discipline (round-2 lesson: 64-VGPR cap spilled 51 MB):
//   launch_bounds(256,2) -> 128 VGPR cap. d-loop split into TWO sweeps so
//   live accums are 51 then 96+4; no big staging arrays, b128 LDS reads
//   consumed immediately.

#define DEV __device__ __forceinline__

DEV constexpr int pid2(int a, int b) {
  int x = a < b ? a : b;
  int y = a < b ? b : a;
  return x * (9 - x) / 2 + y;            // 15 symmetric pairs, lexicographic
}
DEV constexpr int tid3(int i, int j, int k) {
  int a = i, b = j, c = k, t;
  if (a > b) { t = a; a = b; b = t; }
  if (b > c) { t = b; b = c; c = t; }
  if (a > b) { t = a; a = b; b = t; }
  return a * (a * a - 18 * a + 107) / 6 + (b - a) * (11 - a - b) / 2 + (c - b);
}

// Feature row: 64 floats = 16 b128 groups, physical group = g ^ (d & 15):
//   floats  0..34 : triples v_a v_b v_c   (pad 35)        groups 0..8
//   floats 36..40 : S^2 * v_i                             group  9 (+40 in 10)
//   float  41     : S^3   (pads 42,43)                    group 10
//   floats 44..58 : S * pair_t             (pad 59)       groups 11..14
//   group 15 unused.
// Writes: 64 lanes x b128, swizzle spreads 16-lane sets over all banks ->
// conflict-free. Reads are wave-uniform broadcasts (layout-agnostic).

__global__ __launch_bounds__(256, 2)
void dota2_eq3_kernel(const int* __restrict__ x,
                      const float* __restrict__ embed,
                      const float* __restrict__ coefs1, const float* __restrict__ bias1,
                      const float* __restrict__ wout1,  const float* __restrict__ bout1,
                      const float* __restrict__ coefs2, const float* __restrict__ bias2,
                      const float* __restrict__ wout2,  const float* __restrict__ bout2,
                      const float* __restrict__ fcw,    const float* __restrict__ fcb,
                      float* __restrict__ out)
{
  __shared__ __align__(16) float Feat[2][64][64];
  __shared__ __align__(16) float hbarL[2][128];
  __shared__ __align__(16) float zL[256];

  const int n    = blockIdx.x;
  const int tid  = threadIdx.x;
  const int side = tid >> 7;          // waves 0,1 -> side 0; waves 2,3 -> side 1
  const int t2   = tid & 127;

  // ---------- Phase A: build per-d feature rows (threads t2<64, d=t2) ----------
  if (t2 < 64) {
    const int d = t2;
    const int* xn = x + n * 10 + side * 5;
    float v[5];
    #pragma unroll
    for (int i = 0; i < 5; ++i) v[i] = fmaxf(embed[xn[i] * 64 + d], 0.f);
    const float S  = v[0] + v[1] + v[2] + v[3] + v[4];
    const float S2 = S * S;
    const float S3 = S2 * S;
    float p2[15];
    {
      int c2 = 0;
      #pragma unroll
      for (int a = 0; a < 5; ++a)
        #pragma unroll
        for (int b = a; b < 5; ++b) { p2[c2] = v[a] * v[b]; ++c2; }
    }
    alignas(16) float fr[60];
    {
      int c3 = 0;
      #pragma unroll
      for (int a = 0; a < 5; ++a)
        #pragma unroll
        for (int b = a; b < 5; ++b)
          #pragma unroll
          for (int c = b; c < 5; ++c) { fr[c3] = p2[pid2(a, b)] * v[c]; ++c3; }
    }
    fr[35] = 0.f;
    #pragma unroll
    for (int i = 0; i < 5; ++i)  fr[36 + i] = S2 * v[i];
    fr[41] = S3;
    fr[42] = 0.f; fr[43] = 0.f;
    #pragma unroll
    for (int t = 0; t < 15; ++t) fr[44 + t] = S * p2[t];
    fr[59] = 0.f;

    const int sw = d & 15;
    const float4* frv = reinterpret_cast<const float4*>(fr);
    float* row = &Feat[side][d][0];
    #pragma unroll
    for (int g = 0; g < 15; ++g)
      *reinterpret_cast<float4*>(row + ((g ^ sw) << 2)) = frv[g];
  }
  __syncthreads();

  // ---------- Phase B: contraction over d (thread = channel s) ----------
  const int s = t2;
  const float* Cb = side ? coefs2 : coefs1;
  const float* bi = side ? bias2  : bias1;
  const float* Cs = Cb + s * 8;       // coefs[d][s][b], b contiguous, 32B-aligned

  float g0[35], m4[5], m5[5], m6[5];
  float a7 = 0.f;
  #pragma unroll
  for (int t = 0; t < 35; ++t) g0[t] = 0.f;
  #pragma unroll
  for (int t = 0; t < 5; ++t)  { m4[t] = 0.f; m5[t] = 0.f; m6[t] = 0.f; }

  // Sweep A: g0 (cA.x), m4/m5/m6 (cB.xyz), a7 (cB.w). 51 accums live.
  #pragma unroll 1
  for (int d = 0; d < 64; ++d) {
    const float* cp = Cs + (size_t)d * 1024;
    const float cax = cp[0];
    const float4 cB = *reinterpret_cast<const float4*>(cp + 4);
    const float* Fd = &Feat[side][d][0];
    const int sw = d & 15;
    #pragma unroll
    for (int g = 0; g < 8; ++g) {
      const float4 f = *reinterpret_cast<const float4*>(Fd + ((g ^ sw) << 2));
      g0[g * 4 + 0] = fmaf(cax, f.x, g0[g * 4 + 0]);
      g0[g * 4 + 1] = fmaf(cax, f.y, g0[g * 4 + 1]);
      g0[g * 4 + 2] = fmaf(cax, f.z, g0[g * 4 + 2]);
      if (g < 8) {
        if (g * 4 + 3 < 35) g0[g * 4 + 3] = fmaf(cax, f.w, g0[g * 4 + 3]);
      }
    }
    {
      const float4 f8 = *reinterpret_cast<const float4*>(Fd + ((8 ^ sw) << 2));   // 32..35
      g0[32] = fmaf(cax, f8.x, g0[32]);
      g0[33] = fmaf(cax, f8.y, g0[33]);
      g0[34] = fmaf(cax, f8.z, g0[34]);
      const float4 f9 = *reinterpret_cast<const float4*>(Fd + ((9 ^ sw) << 2));   // 36..39
      m4[0] = fmaf(cB.x, f9.x, m4[0]); m5[0] = fmaf(cB.y, f9.x, m5[0]); m6[0] = fmaf(cB.z, f9.x, m6[0]);
      m4[1] = fmaf(cB.x, f9.y, m4[1]); m5[1] = fmaf(cB.y, f9.y, m5[1]); m6[1] = fmaf(cB.z, f9.y, m6[1]);
      m4[2] = fmaf(cB.x, f9.z, m4[2]); m5[2] = fmaf(cB.y, f9.z, m5[2]); m6[2] = fmaf(cB.z, f9.z, m6[2]);
      m4[3] = fmaf(cB.x, f9.w, m4[3]); m5[3] = fmaf(cB.y, f9.w, m5[3]); m6[3] = fmaf(cB.z, f9.w, m6[3]);
      const float4 fA = *reinterpret_cast<const float4*>(Fd + ((10 ^ sw) << 2));  // 40..43
      m4[4] = fmaf(cB.x, fA.x, m4[4]); m5[4] = fmaf(cB.y, fA.x, m5[4]); m6[4] = fmaf(cB.z, fA.x, m6[4]);
      a7 = fmaf(cB.w, fA.y, a7);
    }
  }

  float b1a[15], b2a[15], b3a[15];
  #pragma unroll
  for (int t = 0; t < 15; ++t) { b1a[t] = 0.f; b2a[t] = 0.f; b3a[t] = 0.f; }

  // Sweep B: b1/b2/b3 (cA.yzw). 45 new accums; 96 total live, + 4 F + 4 coef.
  #pragma unroll 1
  for (int d = 0; d < 64; ++d) {
    const float4 cA = *reinterpret_cast<const float4*>(Cs + (size_t)d * 1024);
    const float* Fd = &Feat[side][d][0];
    const int sw = d & 15;
    #pragma unroll
    for (int g = 0; g < 4; ++g) {
      const float4 f = *reinterpret_cast<const float4*>(Fd + (((11 + g) ^ sw) << 2));
      const int t0 = g * 4;
      b1a[t0 + 0] = fmaf(cA.y, f.x, b1a[t0 + 0]);
      b2a[t0 + 0] = fmaf(cA.z, f.x, b2a[t0 + 0]);
      b3a[t0 + 0] = fmaf(cA.w, f.x, b3a[t0 + 0]);
      b1a[t0 + 1] = fmaf(cA.y, f.y, b1a[t0 + 1]);
      b2a[t0 + 1] = fmaf(cA.z, f.y, b2a[t0 + 1]);
      b3a[t0 + 1] = fmaf(cA.w, f.y, b3a[t0 + 1]);
      b1a[t0 + 2] = fmaf(cA.y, f.z, b1a[t0 + 2]);
      b2a[t0 + 2] = fmaf(cA.z, f.z, b2a[t0 + 2]);
      b3a[t0 + 2] = fmaf(cA.w, f.z, b3a[t0 + 2]);
      if (t0 + 3 < 15) {
        b1a[t0 + 3] = fmaf(cA.y, f.w, b1a[t0 + 3]);
        b2a[t0 + 3] = fmaf(cA.z, f.w, b2a[t0 + 3]);
        b3a[t0 + 3] = fmaf(cA.w, f.w, b3a[t0 + 3]);
      }
    }
  }

  // ---------- Assembly: mean of relu over 125 positions (constexpr indices) ----------
  float hsum = 0.f;
  const float base = a7 + bi[s];
  #pragma unroll
  for (int i = 0; i < 5; ++i) {
    const float pi = base + m6[i];
    #pragma unroll
    for (int j = 0; j < 5; ++j) {
      const float pij = pi + m5[j] + b3a[pid2(i, j)];
      #pragma unroll
      for (int k = 0; k < 5; ++k) {
        const float val = pij + m4[k] + b2a[pid2(i, k)] + b1a[pid2(j, k)] + g0[tid3(i, j, k)];
        hsum += fmaxf(val, 0.f);
      }
    }
  }
  hbarL[side][s] = hsum * (1.f / 125.f);
  __syncthreads();

  // ---------- Phase C: te[o] = relu(hbar @ wout + bout), per side ----------
  {
    const int o = t2;
    const float* W  = side ? wout2 : wout1;
    const float* bo = side ? bout2 : bout1;
    const float* hb = &hbarL[side][0];
    float a0 = 0.f, a1 = 0.f, a2 = 0.f, a3 = 0.f;
    #pragma unroll 4
    for (int ss = 0; ss < 128; ss += 4) {
      a0 = fmaf(hb[ss + 0], W[(ss + 0) * 128 + o], a0);
      a1 = fmaf(hb[ss + 1], W[(ss + 1) * 128 + o], a1);
      a2 = fmaf(hb[ss + 2], W[(ss + 2) * 128 + o], a2);
      a3 = fmaf(hb[ss + 3], W[(ss + 3) * 128 + o], a3);
    }
    zL[side * 128 + o] = fmaxf(bo[o] + ((a0 + a1) + (a2 + a3)), 0.f);
  }
  __syncthreads();

  // ---------- Phase D: final FC (256 -> 2), wave-parallel ----------
  if (tid < 64) {
    const float4 zq = *reinterpret_cast<const float4*>(&zL[tid * 4]);
    const int q = tid * 4;
    float p0 = 0.f, p1 = 0.f;
    p0 = fmaf(zq.x, fcw[(q + 0) * 2 + 0], p0);
    p1 = fmaf(zq.x, fcw[(q + 0) * 2 + 1], p1);
    p0 = fmaf(zq.y, fcw[(q + 1) * 2 + 0], p0);
    p1 = fmaf(zq.y, fcw[(q + 1) * 2 + 1], p1);
    p0 = fmaf(zq.z, fcw[(q + 2) * 2 + 0], p0);
    p1 = fmaf(zq.z, fcw[(q + 2) * 2 + 1], p1);
    p0 = fmaf(zq.w, fcw[(q + 3) * 2 + 0], p0);
    p1 = fmaf(zq.w, fcw[(q + 3) * 2 + 1], p1);
    #pragma unroll
    for (int off = 32; off; off >>= 1) {
      p0 += __shfl_down(p0, off);
      p1 += __shfl_down(p1, off);
    }
    if (tid == 0) {
      out[n * 2 + 0] = p0 + fcb[0];
      out[n * 2 + 1] = p1 + fcb[1];
    }
  }
}

extern "C" void kernel_launch(void* const* d_in, const int* in_sizes, int n_in,
                              void* d_out, int out_size, void* d_ws, size_t ws_size,
                              hipStream_t stream) {
  const int*   x      = (const int*)  d_in[0];
  const float* embed  = (const float*)d_in[1];
  const float* coefs1 = (const float*)d_in[2];
  const float* bias1  = (const float*)d_in[3];
  const float* wout1  = (const float*)d_in[4];
  const float* bout1  = (const float*)d_in[5];
  const float* coefs2 = (const float*)d_in[6];
  const float* bias2  = (const float*)d_in[7];
  const float* wout2  = (const float*)d_in[8];
  const float* bout2  = (const float*)d_in[9];
  const float* fcw    = (const float*)d_in[10];
  const float* fcb    = (const float*)d_in[11];
  float* out = (float*)d_out;

  const int batch = in_sizes[0] / 10;   // x: (B, 2, 5)
  dota2_eq3_kernel<<<batch, 256, 0, stream>>>(
      x, embed, coefs1, bias1, wout1, bout1,
      coefs2, bias2, wout2, bout2, fcw, fcb, out);
}

// Round 4
// 95.940 us; speedup vs baseline: 3.9893x; 1.4159x over previous
//
#include <hip/hip_runtime.h>

// Dota2Eq3Embed, MFMA version.
// Per (n, side): v[i][d] = relu(embed[x[n,side,i]][d]); the 8 equivariant
// basis contractions of the rank-1 cube reduce to per-channel tables over
// {v_a v_b v_c, S*pair, S^2*v, S^3}. Tables computed as 3 bf16 GEMMs
// (mfma_f32_16x16x32_bf16), K=64 over d:
//   bank0:   C0^T (128x64)        x F3   (64x35 pad 48) -> cols 0..34
//   banks1-3:[C1;C2;C3] (384x64)  x Fp   (64x15 pad 16) -> cols 35..79
//   banks4-7:[C4..C7]   (512x64)  x [S2v|S3] (64x6 pad 16) -> cols 80..95
// Assembly (125-cell relu mean), hbar@wout, FC stay f32 VALU.
// Coefs pre-converted to bf16 CT[side][b][s][d] in d_ws by cvt kernel.

typedef __attribute__((ext_vector_type(8))) short bf16x8;
typedef __attribute__((ext_vector_type(4))) float f32x4;

#define DEV __device__ __forceinline__

DEV constexpr int pid2(int a, int b) {
  int x = a < b ? a : b;
  int y = a < b ? b : a;
  return x * (9 - x) / 2 + y;            // 15 symmetric pairs
}
DEV constexpr int tid3(int i, int j, int k) {
  int a = i, b = j, c = k, t;
  if (a > b) { t = a; a = b; b = t; }
  if (b > c) { t = b; b = c; c = t; }
  if (a > b) { t = a; a = b; b = t; }
  return a * (a * a - 18 * a + 107) / 6 + (b - a) * (11 - a - b) / 2 + (c - b);
}

DEV ushort f2bf(float f) {            // f32 -> bf16 round-to-nearest-even
  unsigned u = __builtin_bit_cast(unsigned, f);
  return (ushort)((u + 0x7FFFu + ((u >> 16) & 1u)) >> 16);
}

// ---------- prep: coefs (64,128,8) f32 -> CT[side][b][s][d] bf16 ----------
__global__ __launch_bounds__(256)
void cvt_coefs_kernel(const float* __restrict__ c1, const float* __restrict__ c2,
                      ushort* __restrict__ ct) {
  const int idx = blockIdx.x * 256 + threadIdx.x;    // [0, 2*8*128*64)
  const int d    = idx & 63;
  const int s    = (idx >> 6) & 127;
  const int b    = (idx >> 13) & 7;
  const int side = idx >> 16;
  const float* src = side ? c2 : c1;
  ct[idx] = f2bf(src[(d * 128 + s) * 8 + b]);
}

// FT row map (per side), rows t, cols d (stride 72 bf16, 16B-aligned):
//   rows 0..34  : triples v_a v_b v_c (lex a<=b<=c)   [pad rows 35..47 = 0]
//   rows 48..62 : S * pair_t                          [row 63 = 0]
//   rows 64..68 : S^2 * v_i ;  row 69 : S^3           [rows 70..79 = 0]

__global__ __launch_bounds__(256, 2)
void dota2_eq3_mfma(const int* __restrict__ x, const float* __restrict__ embed,
                    const float* __restrict__ bias1, const float* __restrict__ wout1,
                    const float* __restrict__ bout1,
                    const float* __restrict__ bias2, const float* __restrict__ wout2,
                    const float* __restrict__ bout2,
                    const float* __restrict__ fcw, const float* __restrict__ fcb,
                    const ushort* __restrict__ ct, float* __restrict__ out)
{
  __shared__ __align__(16) ushort FT[2][80][72];   // 23040 B
  __shared__ __align__(16) float  OUT[128][100];   // 51200 B
  __shared__ float hbarL[2][128];
  __shared__ float zL[256];

  const int n   = blockIdx.x;
  const int tid = threadIdx.x;
  const int w   = tid >> 6;       // wave 0..3 -> s range [32w, 32w+32)
  const int l   = tid & 63;
  const int grp = l >> 4;         // 0..3
  const int lc  = l & 15;

  // ---- zero FT (pad rows/cols) ----
  {
    unsigned long long* f8 = (unsigned long long*)&FT[0][0][0];   // 2880 qwords
    #pragma unroll 4
    for (int i = tid; i < 2880; i += 256) f8[i] = 0ULL;
  }
  __syncthreads();

  // ---- Phase A: features -> FT bf16 (threads (tid&127)<64; d = tid&63) ----
  if ((tid & 127) < 64) {
    const int side = tid >> 7;
    const int d = tid & 63;
    const int* xn = x + n * 10 + side * 5;
    float v[5];
    #pragma unroll
    for (int i = 0; i < 5; ++i) v[i] = fmaxf(embed[xn[i] * 64 + d], 0.f);
    const float S  = v[0] + v[1] + v[2] + v[3] + v[4];
    const float S2 = S * S;
    const float S3 = S2 * S;
    float p2[15];
    {
      int c2 = 0;
      #pragma unroll
      for (int a = 0; a < 5; ++a)
        #pragma unroll
        for (int b = a; b < 5; ++b) { p2[c2] = v[a] * v[b]; ++c2; }
    }
    ushort* colp = &FT[side][0][d];          // + row*72
    {
      int c3 = 0;
      #pragma unroll
      for (int a = 0; a < 5; ++a)
        #pragma unroll
        for (int b = a; b < 5; ++b)
          #pragma unroll
          for (int c = b; c < 5; ++c) { colp[c3 * 72] = f2bf(p2[pid2(a, b)] * v[c]); ++c3; }
    }
    #pragma unroll
    for (int t = 0; t < 15; ++t) colp[(48 + t) * 72] = f2bf(S * p2[t]);
    #pragma unroll
    for (int i = 0; i < 5; ++i)  colp[(64 + i) * 72] = f2bf(S2 * v[i]);
    colp[69 * 72] = f2bf(S3);
  }
  __syncthreads();

  // ---- per side: GEMMs -> OUT table, then assembly -> hbar ----
  #pragma unroll 1
  for (int side = 0; side < 2; ++side) {
    const ushort* CTs = ct + side * (8 * 128 * 64);

    auto afrag = [&](int b, int s0, int h) -> bf16x8 {
      const ushort* rp = CTs + (b * 128 + s0 + lc) * 64;
      return *(const bf16x8*)(rp + 32 * h + 8 * grp);
    };
    auto bfrag = [&](int t0, int h) -> bf16x8 {
      return *(const bf16x8*)(&FT[side][t0 + lc][32 * h + 8 * grp]);
    };
    auto dwrite = [&](const f32x4& acc, int s0, int colbase, int nvalid) {
      if (lc < nvalid) {
        float* p = &OUT[s0 + 4 * grp][colbase + lc];
        p[0] = acc[0]; p[100] = acc[1]; p[200] = acc[2]; p[300] = acc[3];
      }
    };

    // GEMM-A: bank0, cols 0..34
    {
      const bf16x8 A00 = afrag(0, 32 * w,      0), A01 = afrag(0, 32 * w,      1);
      const bf16x8 A10 = afrag(0, 32 * w + 16, 0), A11 = afrag(0, 32 * w + 16, 1);
      #pragma unroll
      for (int nt = 0; nt < 3; ++nt) {
        const bf16x8 B0 = bfrag(nt * 16, 0), B1 = bfrag(nt * 16, 1);
        const int nvalid = (nt == 2) ? 3 : 16;
        f32x4 acc0 = {0.f, 0.f, 0.f, 0.f};
        acc0 = __builtin_amdgcn_mfma_f32_16x16x32_bf16(A00, B0, acc0, 0, 0, 0);
        acc0 = __builtin_amdgcn_mfma_f32_16x16x32_bf16(A01, B1, acc0, 0, 0, 0);
        dwrite(acc0, 32 * w, nt * 16, nvalid);
        f32x4 acc1 = {0.f, 0.f, 0.f, 0.f};
        acc1 = __builtin_amdgcn_mfma_f32_16x16x32_bf16(A10, B0, acc1, 0, 0, 0);
        acc1 = __builtin_amdgcn_mfma_f32_16x16x32_bf16(A11, B1, acc1, 0, 0, 0);
        dwrite(acc1, 32 * w + 16, nt * 16, nvalid);
      }
    }
    // GEMM-B: banks 1..3 x Fp, cols 35 + (b-1)*15
    {
      const bf16x8 B0 = bfrag(48, 0), B1 = bfrag(48, 1);
      #pragma unroll
      for (int b = 1; b <= 3; ++b)
        #pragma unroll
        for (int u = 0; u < 2; ++u) {
          const int s0 = 32 * w + 16 * u;
          const bf16x8 A0 = afrag(b, s0, 0), A1 = afrag(b, s0, 1);
          f32x4 acc = {0.f, 0.f, 0.f, 0.f};
          acc = __builtin_amdgcn_mfma_f32_16x16x32_bf16(A0, B0, acc, 0, 0, 0);
          acc = __builtin_amdgcn_mfma_f32_16x16x32_bf16(A1, B1, acc, 0, 0, 0);
          dwrite(acc, s0, 35 + (b - 1) * 15, 15);
        }
    }
    // GEMM-C: banks 4..6 -> cols 80+(b-4)*5 (5 valid); bank7 -> col 95 (lane n==5)
    {
      const bf16x8 B0 = bfrag(64, 0), B1 = bfrag(64, 1);
      #pragma unroll
      for (int b = 4; b <= 6; ++b)
        #pragma unroll
        for (int u = 0; u < 2; ++u) {
          const int s0 = 32 * w + 16 * u;
          const bf16x8 A0 = afrag(b, s0, 0), A1 = afrag(b, s0, 1);
          f32x4 acc = {0.f, 0.f, 0.f, 0.f};
          acc = __builtin_amdgcn_mfma_f32_16x16x32_bf16(A0, B0, acc, 0, 0, 0);
          acc = __builtin_amdgcn_mfma_f32_16x16x32_bf16(A1, B1, acc, 0, 0, 0);
          dwrite(acc, s0, 80 + (b - 4) * 5, 5);
        }
      #pragma unroll
      for (int u = 0; u < 2; ++u) {
        const int s0 = 32 * w + 16 * u;
        const bf16x8 A0 = afrag(7, s0, 0), A1 = afrag(7, s0, 1);
        f32x4 acc = {0.f, 0.f, 0.f, 0.f};
        acc = __builtin_amdgcn_mfma_f32_16x16x32_bf16(A0, B0, acc, 0, 0, 0);
        acc = __builtin_amdgcn_mfma_f32_16x16x32_bf16(A1, B1, acc, 0, 0, 0);
        if (lc == 5) {
          float* p = &OUT[s0 + 4 * grp][95];
          p[0] = acc[0]; p[100] = acc[1]; p[200] = acc[2]; p[300] = acc[3];
        }
      }
    }
    __syncthreads();

    // ---- assembly: mean of relu over 125 cells (threads tid<128, s=tid) ----
    if (tid < 128) {
      const int s = tid;
      float T[96];
      const f32x4* rp = (const f32x4*)(&OUT[s][0]);
      #pragma unroll
      for (int j = 0; j < 24; ++j) {
        const f32x4 q = rp[j];
        T[4 * j] = q[0]; T[4 * j + 1] = q[1]; T[4 * j + 2] = q[2]; T[4 * j + 3] = q[3];
      }
      const float* bi = side ? bias2 : bias1;
      const float base = T[95] + bi[s];
      float hsum = 0.f;
      #pragma unroll
      for (int i = 0; i < 5; ++i) {
        const float pi = base + T[90 + i];
        #pragma unroll
        for (int j = 0; j < 5; ++j) {
          const float pij = pi + T[85 + j] + T[65 + pid2(i, j)];
          #pragma unroll
          for (int k = 0; k < 5; ++k) {
            const float val = pij + T[80 + k] + T[50 + pid2(i, k)] + T[35 + pid2(j, k)]
                            + T[tid3(i, j, k)];
            hsum += fmaxf(val, 0.f);
          }
        }
      }
      hbarL[side][s] = hsum * (1.f / 125.f);
    }
    __syncthreads();
  }

  // ---- Phase C: z = relu(hbar @ wout + bout), per side ----
  {
    const int side = tid >> 7;
    const int o = tid & 127;
    const float* W  = side ? wout2 : wout1;
    const float* bo = side ? bout2 : bout1;
    const float* hb = &hbarL[side][0];
    float a0 = 0.f, a1 = 0.f, a2 = 0.f, a3 = 0.f;
    #pragma unroll 4
    for (int ss = 0; ss < 128; ss += 4) {
      a0 = fmaf(hb[ss + 0], W[(ss + 0) * 128 + o], a0);
      a1 = fmaf(hb[ss + 1], W[(ss + 1) * 128 + o], a1);
      a2 = fmaf(hb[ss + 2], W[(ss + 2) * 128 + o], a2);
      a3 = fmaf(hb[ss + 3], W[(ss + 3) * 128 + o], a3);
    }
    zL[side * 128 + o] = fmaxf(bo[o] + ((a0 + a1) + (a2 + a3)), 0.f);
  }
  __syncthreads();

  // ---- Phase D: final FC (256 -> 2), wave 0 ----
  if (tid < 64) {
    const float4 zq = *reinterpret_cast<const float4*>(&zL[tid * 4]);
    const int q = tid * 4;
    float p0 = 0.f, p1 = 0.f;
    p0 = fmaf(zq.x, fcw[(q + 0) * 2 + 0], p0);
    p1 = fmaf(zq.x, fcw[(q + 0) * 2 + 1], p1);
    p0 = fmaf(zq.y, fcw[(q + 1) * 2 + 0], p0);
    p1 = fmaf(zq.y, fcw[(q + 1) * 2 + 1], p1);
    p0 = fmaf(zq.z, fcw[(q + 2) * 2 + 0], p0);
    p1 = fmaf(zq.z, fcw[(q + 2) * 2 + 1], p1);
    p0 = fmaf(zq.w, fcw[(q + 3) * 2 + 0], p0);
    p1 = fmaf(zq.w, fcw[(q + 3) * 2 + 1], p1);
    #pragma unroll
    for (int off = 32; off; off >>= 1) {
      p0 += __shfl_down(p0, off);
      p1 += __shfl_down(p1, off);
    }
    if (tid == 0) {
      out[n * 2 + 0] = p0 + fcb[0];
      out[n * 2 + 1] = p1 + fcb[1];
    }
  }
}

extern "C" void kernel_launch(void* const* d_in, const int* in_sizes, int n_in,
                              void* d_out, int out_size, void* d_ws, size_t ws_size,
                              hipStream_t stream) {
  const int*   x      = (const int*)  d_in[0];
  const float* embed  = (const float*)d_in[1];
  const float* coefs1 = (const float*)d_in[2];
  const float* bias1  = (const float*)d_in[3];
  const float* wout1  = (const float*)d_in[4];
  const float* bout1  = (const float*)d_in[5];
  const float* coefs2 = (const float*)d_in[6];
  const float* bias2  = (const float*)d_in[7];
  const float* wout2  = (const float*)d_in[8];
  const float* bout2  = (const float*)d_in[9];
  const float* fcw    = (const float*)d_in[10];
  const float* fcb    = (const float*)d_in[11];
  float* out  = (float*)d_out;
  ushort* ct  = (ushort*)d_ws;                    // 2*8*128*64*2 = 256 KiB

  const int batch = in_sizes[0] / 10;             // x: (B, 2, 5)
  cvt_coefs_kernel<<<512, 256, 0, stream>>>(coefs1, coefs2, ct);
  dota2_eq3_mfma<<<batch, 256, 0, stream>>>(
      x, embed, bias1, wout1, bout1, bias2, wout2, bout2, fcw, fcb, ct, out);
}